// Round 11
// baseline (378.048 us; speedup 1.0000x reference)
//
#include <hip/hip_runtime.h>

typedef _Float16 f16;
typedef _Float16 f16x8 __attribute__((ext_vector_type(8)));
typedef float f32x4 __attribute__((ext_vector_type(4)));

#define SEQ   196
#define EMB   768
#define NHEAD 12
#define HD    64
#define BATCH 256
#define TOK   (BATCH*SEQ)      /* 50176 */
#define QKVN  (3*EMB)          /* 2304  */
#define CLSK  (SEQ*EMB)        /* 150528 */

#define GLD16(gp, lp) __builtin_amdgcn_global_load_lds( \
    (const __attribute__((address_space(1))) void*)(gp), \
    (__attribute__((address_space(3))) void*)(lp), 16, 0, 0)

// ---------------- f32 -> f16 convert, 8 elems/thread ----------------
__global__ __launch_bounds__(256) void k_cvt8(const float* __restrict__ in,
                                              f16* __restrict__ out, int n8) {
  int i = blockIdx.x * 256 + threadIdx.x;
  if (i >= n8) return;
  const float4* p = (const float4*)in + (size_t)i * 2;
  float4 a = p[0], b = p[1];
  f16x8 o;
  o[0]=(f16)a.x; o[1]=(f16)a.y; o[2]=(f16)a.z; o[3]=(f16)a.w;
  o[4]=(f16)b.x; o[5]=(f16)b.y; o[6]=(f16)b.z; o[7]=(f16)b.w;
  *((f16x8*)out + i) = o;
}

// ------------- W[K][N] f32 -> WT[N][K] f16 (tiled transpose) -------------
__global__ __launch_bounds__(256) void k_transpose_cvt(const float* __restrict__ W,
                                                       f16* __restrict__ WT,
                                                       int K, int N) {
  __shared__ float tile[32][33];
  int n0 = blockIdx.x * 32, k0 = blockIdx.y * 32;
  int t = threadIdx.x, tx = t & 31, ty = t >> 5;
  #pragma unroll
  for (int i = 0; i < 4; ++i) {
    int r = ty + i * 8;
    tile[r][tx] = W[(size_t)(k0 + r) * N + n0 + tx];
  }
  __syncthreads();
  #pragma unroll
  for (int i = 0; i < 4; ++i) {
    int r = ty + i * 8;
    WT[(size_t)(n0 + r) * K + k0 + tx] = (f16)tile[tx][r];
  }
}

// ------------- de-interleave cls_w [S*E,3] -> cls16[c*196+s][e] f16 -------
__global__ __launch_bounds__(256) void k_extract_cls(const float* __restrict__ cls_w,
                                                     f16* __restrict__ cls16,
                                                     float* __restrict__ zbias) {
  int idx = blockIdx.x * 256 + threadIdx.x;       // < 588*768 exactly
  int r = idx / EMB, e = idx - r * EMB;
  int c = r / SEQ, s = r - c * SEQ;
  cls16[(size_t)r * EMB + e] = (f16)cls_w[((size_t)s * EMB + e) * 3 + c];
  if (blockIdx.x == 0)
    for (int i = threadIdx.x; i < EMB; i += 256) zbias[i] = 0.f;
}

// ------- const3 stage 1: partial[s][c] = sum_e out_b[e]*cls_w[s,e,c] -------
__global__ __launch_bounds__(256) void k_const3a(const float* __restrict__ out_b,
                                                 const float* __restrict__ cls_w,
                                                 float* __restrict__ partial) {
  int s = blockIdx.x, t = threadIdx.x;
  float a0 = 0.f, a1 = 0.f, a2 = 0.f;
  for (int e = t; e < EMB; e += 256) {
    float ob = out_b[e];
    const float* p = cls_w + ((size_t)s * EMB + e) * 3;
    a0 += ob * p[0]; a1 += ob * p[1]; a2 += ob * p[2];
  }
  __shared__ float r0[256], r1[256], r2[256];
  r0[t] = a0; r1[t] = a1; r2[t] = a2;
  __syncthreads();
  for (int off = 128; off > 0; off >>= 1) {
    if (t < off) { r0[t] += r0[t + off]; r1[t] += r1[t + off]; r2[t] += r2[t + off]; }
    __syncthreads();
  }
  if (t == 0) { partial[s * 3 + 0] = r0[0]; partial[s * 3 + 1] = r1[0]; partial[s * 3 + 2] = r2[0]; }
}

// ------- const3 stage 2: const3[c] = cls_b[c] + sum_s partial[s][c] --------
__global__ __launch_bounds__(64) void k_const3b(const float* __restrict__ partial,
                                                const float* __restrict__ cls_b,
                                                float* __restrict__ const3) {
  int t = threadIdx.x;
  #pragma unroll
  for (int c = 0; c < 3; ++c) {
    float s = 0.f;
    for (int j = t; j < SEQ; j += 64) s += partial[j * 3 + c];
    #pragma unroll
    for (int off = 32; off > 0; off >>= 1) s += __shfl_down(s, off, 64);
    if (t == 0) const3[c] = s + cls_b[c];
  }
}

// ------- W2c[(c*196+s)][e] f16 -> W2p[(s*768+e)*4+c] f32 (c=3 pad unused) --
__global__ __launch_bounds__(256) void k_make_w2p(const f16* __restrict__ W2c,
                                                  float* __restrict__ W2p) {
  int idx = blockIdx.x * 256 + threadIdx.x;       // < 588*768 exactly
  int r = idx / EMB, e = idx - r * EMB;
  int c = r / SEQ, s = r - c * SEQ;
  W2p[((size_t)s * EMB + e) * 4 + c] = (float)W2c[idx];
}

// ---------------- f16 GEMM (tiny W2 gemm): C = A*B^T + bias --------------
// r2 128x128/BK=64 structure + bijective XCD swizzle.
__global__ __launch_bounds__(256) void k_gemm_bias(
    const f16* __restrict__ A, const f16* __restrict__ Bm,
    const float* __restrict__ bias, f16* __restrict__ C,
    int M, int N, int K) {
  __shared__ f16 As[128 * 64];
  __shared__ f16 Bs[128 * 64];
  const int t = threadIdx.x;
  const int l = t & 63;
  const int w = t >> 6;
  const int wr = w >> 1, wc = w & 1;

  const int nwg = gridDim.x;
  const int orig = blockIdx.x;
  const int q = nwg >> 3, r8 = nwg & 7;
  const int xcd = orig & 7, seq = orig >> 3;
  const int base = xcd < r8 ? xcd * (q + 1) : r8 * (q + 1) + (xcd - r8) * q;
  const int wg = base + seq;
  const int NB = N >> 7;
  const int bm = wg / NB, bn = wg - bm * NB;

  const size_t rowA0 = (size_t)bm * 128, rowB0 = (size_t)bn * 128;
  f32x4 acc[4][4] = {};

  for (int k0 = 0; k0 < K; k0 += 64) {
    if (k0) __syncthreads();
    #pragma unroll
    for (int i = 0; i < 4; ++i) {
      int qq = i * 256 + t;
      int rr = qq >> 3, c = qq & 7;
      int cs = c ^ (rr & 7);
      const f16* ga = A  + (rowA0 + rr) * K + k0 + cs * 8;
      const f16* gb = Bm + (rowB0 + rr) * K + k0 + cs * 8;
      f16* la = As + (size_t)(i * 256 + w * 64) * 8;
      f16* lb = Bs + (size_t)(i * 256 + w * 64) * 8;
      GLD16(ga, la);
      GLD16(gb, lb);
    }
    __syncthreads();
    #pragma unroll
    for (int ks = 0; ks < 2; ++ks) {
      f16x8 av[4], bv[4];
      const int k8 = ks * 4 + (l >> 4);
      #pragma unroll
      for (int m = 0; m < 4; ++m) {
        int rr = wr * 64 + m * 16 + (l & 15);
        av[m] = *(const f16x8*)((const char*)As + rr * 128 + ((k8 ^ (rr & 7)) << 4));
      }
      #pragma unroll
      for (int n = 0; n < 4; ++n) {
        int rr = wc * 64 + n * 16 + (l & 15);
        bv[n] = *(const f16x8*)((const char*)Bs + rr * 128 + ((k8 ^ (rr & 7)) << 4));
      }
      #pragma unroll
      for (int m = 0; m < 4; ++m)
        #pragma unroll
        for (int n = 0; n < 4; ++n)
          acc[m][n] = __builtin_amdgcn_mfma_f32_16x16x32_f16(av[m], bv[n], acc[m][n], 0, 0, 0);
    }
  }
  #pragma unroll
  for (int n = 0; n < 4; ++n) {
    int gcol = bn * 128 + wc * 64 + n * 16 + (l & 15);
    float bs = bias[gcol];
    #pragma unroll
    for (int m = 0; m < 4; ++m) {
      int grow0 = bm * 128 + wr * 64 + m * 16 + (l >> 4) * 4;
      #pragma unroll
      for (int j = 0; j < 4; ++j)
        C[(size_t)(grow0 + j) * N + gcol] = (f16)(acc[m][n][j] + bs);
    }
  }
}

// ---------------- 256x256 8-phase GEMM (r5) + bijective XCD swizzle -------
// r5 deep-stagger schedule (validated): stage tile u+2 in W2/W3/W4, u+3 in
// W6/W7/W8; vmcnt(8) drains at P4/P8 (full tile in flight); conditional
// full drain at tail. NEW (r11): 1D grid + m204 bijective XCD-chunk swizzle
// (bn fastest within bm) -> the 9 blocks sharing a 256-row A-panel land on
// one XCD; r5 was HBM-supply-bound from 5x A-over-fetch (740MB @ 3TB/s).
__global__ __launch_bounds__(512, 2) void k_gemm256(
    const f16* __restrict__ A, const f16* __restrict__ Bm,
    const float* __restrict__ bias, f16* __restrict__ C,
    int M, int N, int K) {
  __shared__ f16 As[2 * 256 * 64];   // 64 KiB
  __shared__ f16 Bs[2 * 256 * 64];   // 64 KiB
  const int t = threadIdx.x;
  const int l = t & 63;
  const int w = t >> 6;              // 0..7
  const int wm = w >> 2;             // 0..1 -> 128-row half
  const int wn = w & 3;              // 0..3 -> 64-col quarter

  const int nwg = gridDim.x;
  const int orig = blockIdx.x;
  const int q = nwg >> 3, r8 = nwg & 7;
  const int xcd = orig & 7, seq = orig >> 3;
  const int base = xcd < r8 ? xcd * (q + 1) : r8 * (q + 1) + (xcd - r8) * q;
  const int wg = base + seq;
  const int NB = N >> 8;             // 256-wide tiles
  const int bm = wg / NB, bn = wg - bm * NB;

  const size_t rowA0 = (size_t)bm * 256, rowB0 = (size_t)bn * 256;
  const int KT = K >> 6;             // 12 (even)

  f32x4 acc[8][4] = {};
  f16x8 a[4][2], b0[2][2], b1[2][2];

  auto stageA = [&](int kt, int rd) {
    if (kt >= KT) return;
    int qq = rd * 512 + t;
    int rr = qq >> 3, c = qq & 7;
    int cs = c ^ (rr & 7);
    GLD16(A + (rowA0 + rr) * (size_t)K + kt * 64 + cs * 8,
          As + (kt & 1) * 16384 + qq * 8);
  };
  auto stageB = [&](int kt, int rd) {
    if (kt >= KT) return;
    int qq = rd * 512 + t;
    int rr = qq >> 3, c = qq & 7;
    int cs = c ^ (rr & 7);
    GLD16(Bm + (rowB0 + rr) * (size_t)K + kt * 64 + cs * 8,
          Bs + (kt & 1) * 16384 + qq * 8);
  };
  auto rdA = [&](int buf, int mi, int kk) -> f16x8 {
    int rr = wm * 128 + mi * 16 + (l & 15);
    int k8 = kk * 4 + (l >> 4);
    return *(const f16x8*)((const char*)As + buf * 32768 + rr * 128 + ((k8 ^ (rr & 7)) << 4));
  };
  auto rdB = [&](int buf, int ni, int kk) -> f16x8 {
    int rr = wn * 64 + ni * 16 + (l & 15);
    int k8 = kk * 4 + (l >> 4);
    return *(const f16x8*)((const char*)Bs + buf * 32768 + rr * 128 + ((k8 ^ (rr & 7)) << 4));
  };
  auto drain = [&](int kt) {
    if (kt < KT) { asm volatile("s_waitcnt vmcnt(8)" ::: "memory"); }
    else         { asm volatile("s_waitcnt vmcnt(0)" ::: "memory"); }
  };

#define PH_SYNC_PRE()  asm volatile("" ::: "memory"); __builtin_amdgcn_s_barrier(); \
                       __builtin_amdgcn_s_setprio(1)
#define PH_SYNC_POST() __builtin_amdgcn_s_setprio(0); asm volatile("" ::: "memory"); \
                       __builtin_amdgcn_s_barrier()

  #pragma unroll
  for (int rd = 0; rd < 4; ++rd) { stageA(0, rd); stageB(0, rd); }
  #pragma unroll
  for (int rd = 0; rd < 4; ++rd) { stageA(1, rd); stageB(1, rd); }
  asm volatile("s_waitcnt vmcnt(8)" ::: "memory");
  __builtin_amdgcn_s_barrier();

  for (int it = 0; it < KT / 2; ++it) {
    const int t2 = 2 * it + 2, t3 = 2 * it + 3;

    // P1: read a=A-mh0, b0=B-h0 (buf0); mfma quad(mh0,nh0)
    #pragma unroll
    for (int i = 0; i < 4; ++i)
      #pragma unroll
      for (int kk = 0; kk < 2; ++kk) a[i][kk] = rdA(0, i, kk);
    #pragma unroll
    for (int ni = 0; ni < 2; ++ni)
      #pragma unroll
      for (int kk = 0; kk < 2; ++kk) b0[ni][kk] = rdB(0, ni, kk);
    PH_SYNC_PRE();
    #pragma unroll
    for (int i = 0; i < 4; ++i)
      #pragma unroll
      for (int ni = 0; ni < 2; ++ni)
        #pragma unroll
        for (int kk = 0; kk < 2; ++kk)
          acc[i][ni] = __builtin_amdgcn_mfma_f32_16x16x32_f16(a[i][kk], b0[ni][kk], acc[i][ni], 0, 0, 0);
    PH_SYNC_POST();

    // P2: read b1 (buf0); stage A(t2, r0/r2); mfma quad(mh0,nh1)
    #pragma unroll
    for (int ni = 0; ni < 2; ++ni)
      #pragma unroll
      for (int kk = 0; kk < 2; ++kk) b1[ni][kk] = rdB(0, 2 + ni, kk);
    stageA(t2, 0); stageA(t2, 2);
    PH_SYNC_PRE();
    #pragma unroll
    for (int i = 0; i < 4; ++i)
      #pragma unroll
      for (int ni = 0; ni < 2; ++ni)
        #pragma unroll
        for (int kk = 0; kk < 2; ++kk)
          acc[i][2 + ni] = __builtin_amdgcn_mfma_f32_16x16x32_f16(a[i][kk], b1[ni][kk], acc[i][2 + ni], 0, 0, 0);
    PH_SYNC_POST();

    // P3: read a=A-mh1 (buf0); stage B(t2, all); mfma quad(mh1,nh1)
    #pragma unroll
    for (int i = 0; i < 4; ++i)
      #pragma unroll
      for (int kk = 0; kk < 2; ++kk) a[i][kk] = rdA(0, 4 + i, kk);
    stageB(t2, 0); stageB(t2, 1); stageB(t2, 2); stageB(t2, 3);
    PH_SYNC_PRE();
    #pragma unroll
    for (int i = 0; i < 4; ++i)
      #pragma unroll
      for (int ni = 0; ni < 2; ++ni)
        #pragma unroll
        for (int kk = 0; kk < 2; ++kk)
          acc[4 + i][2 + ni] = __builtin_amdgcn_mfma_f32_16x16x32_f16(a[i][kk], b1[ni][kk], acc[4 + i][2 + ni], 0, 0, 0);
    PH_SYNC_POST();

    // P4: stage A(t2, r1/r3); drain; mfma quad(mh1,nh0)
    stageA(t2, 1); stageA(t2, 3);
    drain(t2);
    PH_SYNC_PRE();
    #pragma unroll
    for (int i = 0; i < 4; ++i)
      #pragma unroll
      for (int ni = 0; ni < 2; ++ni)
        #pragma unroll
        for (int kk = 0; kk < 2; ++kk)
          acc[4 + i][ni] = __builtin_amdgcn_mfma_f32_16x16x32_f16(a[i][kk], b0[ni][kk], acc[4 + i][ni], 0, 0, 0);
    PH_SYNC_POST();

    // P5: read a, b0 (buf1); mfma quad(mh0,nh0)
    #pragma unroll
    for (int i = 0; i < 4; ++i)
      #pragma unroll
      for (int kk = 0; kk < 2; ++kk) a[i][kk] = rdA(1, i, kk);
    #pragma unroll
    for (int ni = 0; ni < 2; ++ni)
      #pragma unroll
      for (int kk = 0; kk < 2; ++kk) b0[ni][kk] = rdB(1, ni, kk);
    PH_SYNC_PRE();
    #pragma unroll
    for (int i = 0; i < 4; ++i)
      #pragma unroll
      for (int ni = 0; ni < 2; ++ni)
        #pragma unroll
        for (int kk = 0; kk < 2; ++kk)
          acc[i][ni] = __builtin_amdgcn_mfma_f32_16x16x32_f16(a[i][kk], b0[ni][kk], acc[i][ni], 0, 0, 0);
    PH_SYNC_POST();

    // P6: read b1 (buf1); stage A(t3, r0/r2); mfma quad(mh0,nh1)
    #pragma unroll
    for (int ni = 0; ni < 2; ++ni)
      #pragma unroll
      for (int kk = 0; kk < 2; ++kk) b1[ni][kk] = rdB(1, 2 + ni, kk);
    stageA(t3, 0); stageA(t3, 2);
    PH_SYNC_PRE();
    #pragma unroll
    for (int i = 0; i < 4; ++i)
      #pragma unroll
      for (int ni = 0; ni < 2; ++ni)
        #pragma unroll
        for (int kk = 0; kk < 2; ++kk)
          acc[i][2 + ni] = __builtin_amdgcn_mfma_f32_16x16x32_f16(a[i][kk], b1[ni][kk], acc[i][2 + ni], 0, 0, 0);
    PH_SYNC_POST();

    // P7: read a=A-mh1 (buf1); stage B(t3, all); mfma quad(mh1,nh1)
    #pragma unroll
    for (int i = 0; i < 4; ++i)
      #pragma unroll
      for (int kk = 0; kk < 2; ++kk) a[i][kk] = rdA(1, 4 + i, kk);
    stageB(t3, 0); stageB(t3, 1); stageB(t3, 2); stageB(t3, 3);
    PH_SYNC_PRE();
    #pragma unroll
    for (int i = 0; i < 4; ++i)
      #pragma unroll
      for (int ni = 0; ni < 2; ++ni)
        #pragma unroll
        for (int kk = 0; kk < 2; ++kk)
          acc[4 + i][2 + ni] = __builtin_amdgcn_mfma_f32_16x16x32_f16(a[i][kk], b1[ni][kk], acc[4 + i][2 + ni], 0, 0, 0);
    PH_SYNC_POST();

    // P8: stage A(t3, r1/r3); drain; mfma quad(mh1,nh0)
    stageA(t3, 1); stageA(t3, 3);
    drain(t3);
    PH_SYNC_PRE();
    #pragma unroll
    for (int i = 0; i < 4; ++i)
      #pragma unroll
      for (int ni = 0; ni < 2; ++ni)
        #pragma unroll
        for (int kk = 0; kk < 2; ++kk)
          acc[4 + i][ni] = __builtin_amdgcn_mfma_f32_16x16x32_f16(a[i][kk], b0[ni][kk], acc[4 + i][ni], 0, 0, 0);
    PH_SYNC_POST();
  }

  // epilogue: C/D layout col = l&15, row = (l>>4)*4 + j
  #pragma unroll
  for (int ni = 0; ni < 4; ++ni) {
    int gcol = bn * 256 + wn * 64 + ni * 16 + (l & 15);
    float bs = bias[gcol];
    #pragma unroll
    for (int mi = 0; mi < 8; ++mi) {
      int grow0 = bm * 256 + wm * 128 + mi * 16 + (l >> 4) * 4;
      #pragma unroll
      for (int j = 0; j < 4; ++j)
        C[(size_t)(grow0 + j) * N + gcol] = (f16)(acc[mi][ni][j] + bs);
    }
  }
}

// ------- fused per-token attention + folded-classifier partial dot --------
__global__ __launch_bounds__(64) void k_attn_cls(const f16* __restrict__ qkv,
                                                 const float* __restrict__ W2p,
                                                 float* __restrict__ part4) {
  const int s = blockIdx.x, b = blockIdx.y;
  const int tok = b * SEQ + s;
  const int l = threadIdx.x;
  __shared__ f16 row[QKVN];
  __shared__ float sc[144];
  __shared__ float aw[144];
  const uint2* src = (const uint2*)(qkv + (size_t)tok * QKVN);
  uint2* dst = (uint2*)row;
  #pragma unroll
  for (int i = 0; i < 9; ++i) dst[l + i * 64] = src[l + i * 64];
  __syncthreads();
  for (int p = l; p < 144; p += 64) {
    int i = p / 12, j = p - i * 12;
    const f16x8* q8 = (const f16x8*)(row + i * 192);
    const f16x8* k8 = (const f16x8*)(row + j * 192 + 64);
    float sv = 0.f;
    #pragma unroll
    for (int d8 = 0; d8 < 8; ++d8) {
      f16x8 a = q8[d8], bb = k8[d8];
      #pragma unroll
      for (int e = 0; e < 8; ++e) sv += (float)a[e] * (float)bb[e];
    }
    sc[p] = sv * 0.125f;
  }
  __syncthreads();
  if (l < 12) {
    float m = -1e30f;
    #pragma unroll
    for (int j = 0; j < 12; ++j) m = fmaxf(m, sc[l * 12 + j]);
    float e[12], sum = 0.f;
    #pragma unroll
    for (int j = 0; j < 12; ++j) { e[j] = __expf(sc[l * 12 + j] - m); sum += e[j]; }
    float inv = 1.f / sum;
    #pragma unroll
    for (int j = 0; j < 12; ++j) aw[l * 12 + j] = e[j] * inv;
  }
  __syncthreads();
  float vv[12];
  #pragma unroll
  for (int j = 0; j < 12; ++j) vv[j] = (float)row[j * 192 + 128 + l];
  const float4* wrow = (const float4*)W2p + (size_t)s * EMB;
  float s0 = 0.f, s1 = 0.f, s2 = 0.f;
  #pragma unroll
  for (int i = 0; i < 12; ++i) {
    float o = 0.f;
    #pragma unroll
    for (int j = 0; j < 12; ++j) o += aw[i * 12 + j] * vv[j];
    float4 wv = wrow[i * 64 + l];
    s0 += o * wv.x; s1 += o * wv.y; s2 += o * wv.z;
  }
  #pragma unroll
  for (int off = 32; off > 0; off >>= 1) {
    s0 += __shfl_down(s0, off, 64);
    s1 += __shfl_down(s1, off, 64);
    s2 += __shfl_down(s2, off, 64);
  }
  if (l == 0) *(float4*)(part4 + (size_t)tok * 4) = make_float4(s0, s1, s2, 0.f);
}

// ------- final: logits[b,c] = sum_s part4[b,s,c] + const3[c] --------------
__global__ __launch_bounds__(64) void k_cls_final(const float* __restrict__ part4,
                                                  const float* __restrict__ const3,
                                                  float* __restrict__ logits) {
  const int b = blockIdx.x, l = threadIdx.x;
  float s0 = 0.f, s1 = 0.f, s2 = 0.f;
  for (int j = l; j < SEQ; j += 64) {
    float4 p = *(const float4*)(part4 + ((size_t)b * SEQ + j) * 4);
    s0 += p.x; s1 += p.y; s2 += p.z;
  }
  #pragma unroll
  for (int off = 32; off > 0; off >>= 1) {
    s0 += __shfl_down(s0, off, 64);
    s1 += __shfl_down(s1, off, 64);
    s2 += __shfl_down(s2, off, 64);
  }
  if (l == 0) {
    logits[b * 3 + 0] = s0 + const3[0];
    logits[b * 3 + 1] = s1 + const3[1];
    logits[b * 3 + 2] = s2 + const3[2];
  }
}

extern "C" void kernel_launch(void* const* d_in, const int* in_sizes, int n_in,
                              void* d_out, int out_size, void* d_ws, size_t ws_size,
                              hipStream_t stream) {
  (void)in_sizes; (void)n_in; (void)out_size;
  const float* x      = (const float*)d_in[0];
  const float* qkv_w  = (const float*)d_in[1];
  const float* qkv_b  = (const float*)d_in[2];
  const float* out_w  = (const float*)d_in[3];
  const float* out_b  = (const float*)d_in[4];
  const float* cls_w  = (const float*)d_in[5];
  const float* cls_b  = (const float*)d_in[6];
  float* logits = (float*)d_out;

  const size_t SZ_X16 = (size_t)TOK * EMB * 2;      // 77,070,336
  const size_t SZ_QKV = (size_t)TOK * QKVN * 2;     // 231,211,008
  const size_t SZ_QT  = (size_t)QKVN * EMB * 2;     // 3,538,944
  const size_t SZ_OT  = (size_t)EMB * EMB * 2;      // 1,179,648
  if (ws_size < SZ_X16 + SZ_QKV + SZ_QT + SZ_OT) return;

  char* ws = (char*)d_ws;
  const size_t base2 = SZ_X16 + SZ_QKV;
  f16*   x16     = (f16*)ws;
  float* W2p     = (float*)(ws);                        // overlays x16 (post-G1)
  f16*   outw16  = (f16*)(ws + (4u << 20));
  f16*   cls16   = (f16*)(ws + (8u << 20));
  f16*   W2c     = (f16*)(ws + (12u << 20));
  float* partial = (float*)(ws + (16u << 20));
  float* part4   = (float*)(ws + (20u << 20));
  float* zbias   = (float*)(ws + (24u << 20));
  float* const3  = (float*)(ws + (25u << 20));
  f16*   qkvb    = (f16*)(ws + SZ_X16);
  f16*   qkvT    = (f16*)(ws + base2);

  // ---- GEMM1 path: 8-phase 256^2 kernel (r5) + XCD swizzle ----
  k_cvt8<<<dim3(TOK * EMB / 8 / 256), dim3(256), 0, stream>>>(x, x16, TOK * EMB / 8);
  k_transpose_cvt<<<dim3(QKVN / 32, EMB / 32), dim3(256), 0, stream>>>(qkv_w, qkvT, EMB, QKVN);
  k_gemm256<<<dim3((TOK / 256) * (QKVN / 256)), dim3(512), 0, stream>>>(x16, qkvT, qkv_b, qkvb, TOK, QKVN, EMB);
  // ---- folded-classifier prep (x16/qkvT dead; region0 reused) ----
  k_cvt8<<<dim3(EMB * EMB / 8 / 256), dim3(256), 0, stream>>>(out_w, outw16, EMB * EMB / 8);
  k_extract_cls<<<dim3(588 * EMB / 256), dim3(256), 0, stream>>>(cls_w, cls16, zbias);
  k_const3a<<<dim3(SEQ), dim3(256), 0, stream>>>(out_b, cls_w, partial);
  k_const3b<<<dim3(1), dim3(64), 0, stream>>>(partial, cls_b, const3);
  k_gemm_bias<<<dim3((640 / 128) * (EMB / 128)), dim3(256), 0, stream>>>(cls16, outw16, zbias, W2c, 640, EMB, EMB);
  k_make_w2p<<<dim3(588 * EMB / 256), dim3(256), 0, stream>>>(W2c, W2p);
  // ---- fused attention + classifier ----
  k_attn_cls<<<dim3(SEQ, BATCH), dim3(64), 0, stream>>>(qkvb, W2p, part4);
  k_cls_final<<<dim3(BATCH), dim3(64), 0, stream>>>(part4, const3, logits);
}